// Round 5
// baseline (231.217 us; speedup 1.0000x reference)
//
#include <hip/hip_runtime.h>

// Problem constants (fixed by setup_inputs): B=32, C=64, H=W=32, N=16 branches.
#define CH   64
#define NBR  16
#define HW4  256          // float4 per channel plane (H*W = 1024 floats)

typedef float v4f __attribute__((ext_vector_type(4)));

// Grid-barrier counter. Module-scope device memory: zero-initialized at module
// load and NOT re-poisoned by the harness between iterations. Monotonic epoch
// scheme => never needs resetting: each execution of the kernel adds exactly
// 1024; a block spins until its own epoch (1024-aligned) completes.
__device__ int g_ctr;

// ---------------------------------------------------------------------------
// Single fused kernel: stats -> grid barrier -> finalize -> apply.
// grid = 1024 blocks x 256 threads. __launch_bounds__(256,4) = 4 waves/EU min
// -> >=4 blocks/CU resident -> all 1024 blocks co-resident on 256 CUs, so the
// spin barrier cannot deadlock.
//
// Block decode: b = bid&31 (same batch in both phases -> its x slice is warm
// in this XCD's L2 for the apply), pair = bid>>5 (0..31), n = pair&15,
// half = bid>>9.
//
// Phase 1: sums of the 2 channel planes (b, 2*pair), (b, 2*pair+1) — 8 KB per
// block, 8 MiB total, fully coalesced, deterministic partial slots, no atomics.
// Phase 2 (after barrier): threads 0..31 fold the 32 per-batch partials for
// this block's 32 apply-channels into scale/shift; then the R1-proven apply:
// per iteration a 1 KB coalesced wave read of x (L2) and a 1 KB coalesced
// wave write, consecutive iterations contiguous -> one 128 KB store stream
// per block. Plain stores (nt measured +7 us in R3 -> reverted).
// ---------------------------------------------------------------------------
__global__ void __launch_bounds__(256, 4)
bn_fused(const float* __restrict__ x,
         const float* __restrict__ gamma,
         const float* __restrict__ beta,
         float* __restrict__ partials,
         float* __restrict__ out) {
    const int bid  = blockIdx.x;          // 0..1023
    const int b    = bid & 31;
    const int pair = bid >> 5;            // 0..31 -> channels {2p, 2p+1}
    const int n    = pair & 15;
    const int half = bid >> 9;            // 0..1
    const int t    = threadIdx.x;         // 0..255
    const int wave = t >> 6, lane = t & 63;

    __shared__ float ls[4][4];
    __shared__ float sa[32], ss[32];

    // ---------------- phase 1: per-(b, 2 channels) sum/sumsq ----------------
    {
        const v4f* xp = (const v4f*)x + (b * CH + pair * 2) * HW4;
        const v4f v0 = xp[t];            // plane c = 2*pair   (256 f4)
        const v4f v1 = xp[t + 256];      // plane c = 2*pair+1 (256 f4)
        float s0 = v0.x + v0.y + v0.z + v0.w;
        float q0 = v0.x * v0.x + v0.y * v0.y + v0.z * v0.z + v0.w * v0.w;
        float s1 = v1.x + v1.y + v1.z + v1.w;
        float q1 = v1.x * v1.x + v1.y * v1.y + v1.z * v1.z + v1.w * v1.w;
#pragma unroll
        for (int off = 32; off > 0; off >>= 1) {
            s0 += __shfl_down(s0, off);
            q0 += __shfl_down(q0, off);
            s1 += __shfl_down(s1, off);
            q1 += __shfl_down(q1, off);
        }
        if (lane == 0) {
            ls[wave][0] = s0; ls[wave][1] = q0;
            ls[wave][2] = s1; ls[wave][3] = q1;
        }
        __syncthreads();
        if (t == 0) {
            float S0 = 0.f, Q0 = 0.f, S1 = 0.f, Q1 = 0.f;
#pragma unroll
            for (int w = 0; w < 4; ++w) {
                S0 += ls[w][0]; Q0 += ls[w][1];
                S1 += ls[w][2]; Q1 += ls[w][3];
            }
            const int c0 = pair * 2;
            partials[(b * CH + c0)     * 2 + 0] = S0;
            partials[(b * CH + c0)     * 2 + 1] = Q0;
            partials[(b * CH + c0 + 1) * 2 + 0] = S1;
            partials[(b * CH + c0 + 1) * 2 + 1] = Q1;
        }
    }

    // ---------------- grid barrier (poison-immune monotonic epoch) ----------
    __threadfence();                       // release partials to device scope
    __syncthreads();                       // whole block done before arrival
    if (t == 0) {
        const int old = __hip_atomic_fetch_add(&g_ctr, 1, __ATOMIC_ACQ_REL,
                                               __HIP_MEMORY_SCOPE_AGENT);
        const int target = (old - (old & 1023)) + 1024;   // end of my epoch
        while (__hip_atomic_load(&g_ctr, __ATOMIC_ACQUIRE,
                                 __HIP_MEMORY_SCOPE_AGENT) < target)
            __builtin_amdgcn_s_sleep(2);
    }
    __syncthreads();

    // ---------------- phase 2a: fold 32 partials -> scale/shift -------------
    if (t < 32) {
        const int c = half * 32 + t;
        float S = 0.f, Q = 0.f;
#pragma unroll
        for (int bb = 0; bb < 32; ++bb) {
            S += partials[(bb * CH + c) * 2 + 0];
            Q += partials[(bb * CH + c) * 2 + 1];
        }
        const float mean = S * (1.0f / 32768.0f);
        const float var  = Q * (1.0f / 32768.0f) - mean * mean;
        const float inv  = rsqrtf(var + 1e-5f);
        const float a    = gamma[n * CH + c] * inv;
        sa[t] = a;
        ss[t] = beta[n * CH + c] - a * mean;
    }
    __syncthreads();

    // ---------------- phase 2b: apply (R1-proven structure) -----------------
    const v4f* xp = (const v4f*)x   + (b * CH + half * 32) * HW4 + t;
    v4f*       op = (v4f*)out + ((b * NBR + n) * CH + half * 32) * HW4 + t;
#pragma unroll 4
    for (int cc = 0; cc < 32; ++cc) {
        const float a = sa[cc];
        const float s = ss[cc];
        const v4f v = xp[cc * HW4];
        v4f o;
        o.x = fmaf(a, v.x, s);
        o.y = fmaf(a, v.y, s);
        o.z = fmaf(a, v.z, s);
        o.w = fmaf(a, v.w, s);
        op[cc * HW4] = o;
    }
}

extern "C" void kernel_launch(void* const* d_in, const int* in_sizes, int n_in,
                              void* d_out, int out_size, void* d_ws, size_t ws_size,
                              hipStream_t stream) {
    const float* x     = (const float*)d_in[0];   // [32,64,32,32]
    const float* gamma = (const float*)d_in[1];   // [16,64]
    const float* beta  = (const float*)d_in[2];   // [16,64]
    float* out = (float*)d_out;                   // [32,1024,32,32]
    float* ws  = (float*)d_ws;

    float* partials = ws;   // 32*64*2 = 4096 floats, deterministic slots

    bn_fused<<<1024, 256, 0, stream>>>(x, gamma, beta, partials, out);
}

// Round 6
// 145.242 us; speedup vs baseline: 1.5919x; 1.5919x over previous
//
#include <hip/hip_runtime.h>

// Problem constants (fixed by setup_inputs): B=32, C=64, H=W=32, N=16 branches.
#define CH   64
#define NBR  16
#define HW4  256          // float4 per channel plane (H*W = 1024 floats)

typedef float v4f __attribute__((ext_vector_type(4)));

// ---------------------------------------------------------------------------
// Kernel A: per-(batch, channel) sum / sumsq. Proven (~4 µs).
// grid = 512: b = bid & 31, cg = bid >> 5. One wave reduces one channel plane
// (1024 floats, coalesced float4), one deterministic partial slot, no atomics.
// ---------------------------------------------------------------------------
__global__ void __launch_bounds__(256) bn_partial(const float* __restrict__ x,
                                                  float* __restrict__ partials) {
    const int b    = blockIdx.x & 31;
    const int cg   = blockIdx.x >> 5;     // 0..15
    const int wave = threadIdx.x >> 6;    // 0..3
    const int lane = threadIdx.x & 63;
    const int c    = cg * 4 + wave;

    const v4f* xp = (const v4f*)x + (b * CH + c) * HW4;
    float s = 0.f, sq = 0.f;
#pragma unroll
    for (int i = 0; i < 4; ++i) {
        const v4f v = xp[i * 64 + lane];
        s  += v.x + v.y + v.z + v.w;
        sq += v.x * v.x + v.y * v.y + v.z * v.z + v.w * v.w;
    }
#pragma unroll
    for (int off = 32; off > 0; off >>= 1) {
        s  += __shfl_down(s, off);
        sq += __shfl_down(sq, off);
    }
    if (lane == 0) {
        partials[(b * CH + c) * 2 + 0] = s;
        partials[(b * CH + c) * 2 + 1] = sq;
    }
}

// ---------------------------------------------------------------------------
// Kernel B: fused finalize + apply.
//
// ROUND-6 CHANGE (single variable vs R1): TLP. 1024 -> 4096 blocks
// (16 queued/CU, small VGPR -> 8+ resident/CU), 8 planes per block instead of
// 32, so each thread does only 8 independent load+fma+store pairs with all 8
// x-loads hoisted. Per-wave-instruction coalescing is IDENTICAL to R1 (each
// store = 64 lanes x 16 B = 1 KB contiguous; block span = 32 KB contiguous).
// This is also the A/B mirror of R4 (same grid; R4's per-thread-contiguous
// mapping broke wave coalescing and cost +29 µs).
//
// Decode: bid = (b*NBR + n)*8 + g, g = 0..7 -> channels c0 = g*8 .. g*8+7.
// out f4 base = ((b*NBR + n)*CH + g*8)*HW4; x f4 base = (b*CH + g*8)*HW4.
// Preamble: threads 0..7 fold the 32 per-batch partials of this block's 8
// channels into scale/shift in LDS (finalize stays fused; partials = 16 KB,
// L2-resident).
// ---------------------------------------------------------------------------
__global__ void __launch_bounds__(256) bn_apply(const float* __restrict__ x,
                                                const float* __restrict__ partials,
                                                const float* __restrict__ gamma,
                                                const float* __restrict__ beta,
                                                float* __restrict__ out) {
    const int t   = threadIdx.x;            // 0..255
    const int g   = blockIdx.x & 7;         // channel octet
    const int bn  = blockIdx.x >> 3;        // 0..511 = b*16 + n
    const int n   = bn & 15;
    const int b   = bn >> 4;
    const int c0  = g * 8;

    __shared__ float sa[8], ss[8];
    if (t < 8) {
        const int c = c0 + t;
        float S = 0.f, Q = 0.f;
#pragma unroll
        for (int bb = 0; bb < 32; ++bb) {
            S += partials[(bb * CH + c) * 2 + 0];
            Q += partials[(bb * CH + c) * 2 + 1];
        }
        const float mean = S * (1.0f / 32768.0f);
        const float var  = Q * (1.0f / 32768.0f) - mean * mean;
        const float inv  = rsqrtf(var + 1e-5f);
        const float a    = gamma[n * CH + c] * inv;
        sa[t] = a;
        ss[t] = beta[n * CH + c] - a * mean;
    }
    __syncthreads();

    const v4f* xp = (const v4f*)x   + (b * CH + c0) * HW4 + t;
    v4f*       op = (v4f*)out + ((b * NBR + n) * CH + c0) * HW4 + t;

    // All 8 loads issued back-to-back (independent), then 8 fma+store pairs.
    v4f v[8];
#pragma unroll
    for (int cc = 0; cc < 8; ++cc) v[cc] = xp[cc * HW4];
#pragma unroll
    for (int cc = 0; cc < 8; ++cc) {
        const float a = sa[cc];
        const float s = ss[cc];
        v4f o;
        o.x = fmaf(a, v[cc].x, s);
        o.y = fmaf(a, v[cc].y, s);
        o.z = fmaf(a, v[cc].z, s);
        o.w = fmaf(a, v[cc].w, s);
        op[cc * HW4] = o;
    }
}

extern "C" void kernel_launch(void* const* d_in, const int* in_sizes, int n_in,
                              void* d_out, int out_size, void* d_ws, size_t ws_size,
                              hipStream_t stream) {
    const float* x     = (const float*)d_in[0];   // [32,64,32,32]
    const float* gamma = (const float*)d_in[1];   // [16,64]
    const float* beta  = (const float*)d_in[2];   // [16,64]
    float* out = (float*)d_out;                   // [32,1024,32,32]
    float* ws  = (float*)d_ws;

    float* partials = ws;   // 32*64*2 = 4096 floats, deterministic slots

    bn_partial<<<512, 256, 0, stream>>>(x, partials);
    bn_apply  <<<4096, 256, 0, stream>>>(x, partials, gamma, beta, out);
}